// Round 18
// baseline (206.692 us; speedup 1.0000x reference)
//
#include <hip/hip_runtime.h>
#include <cstdint>

#define B_ 16
#define L_ 512
#define N_ 8192
#define K_ 30
#define E_ (N_*K_)
#define H_ 32
#define C_ 35

typedef uint16_t u16;
typedef uint32_t u32;
typedef unsigned long long u64;
typedef float f2v __attribute__((ext_vector_type(2)));

static __device__ __forceinline__ f2v splat2(float x) { f2v v; v.x = x; v.y = x; return v; }

// adaptive float load: bf16 (u16<<16) or fp32
static __device__ __forceinline__ float ldf(const void* p, int i, int bf) {
    return bf ? __uint_as_float(((u32)((const u16*)p)[i]) << 16)
              : ((const float*)p)[i];
}
static __device__ __forceinline__ float bfu16(u16 x) {
    return __uint_as_float(((u32)x) << 16);
}
// mask load: mode 0 = u8 bool, 1 = int32, 2 = int64 (little-endian low word)
static __device__ __forceinline__ int ldmask(const void* p, int i, int mode) {
    if (mode == 0) return ((const unsigned char*)p)[i] != 0;
    if (mode == 2) return ((const u32*)p)[2*i] != 0;
    return ((const u32*)p)[i] != 0;
}
// f32 -> bf16 RNE
static __device__ __forceinline__ u16 f2bf(float f) {
    u32 x = __float_as_uint(f);
    u32 r = x + 0x7FFFu + ((x >> 16) & 1u);
    return (u16)(r >> 16);
}
// fast silu (~1e-7 rel err; threshold 4.3e-3)
static __device__ __forceinline__ float fsilu(float x) {
    return x * __builtin_amdgcn_rcpf(1.f + __expf(-x));
}
// wave-uniform-index register broadcast (SGPR result -> free fmaf operand)
static __device__ __forceinline__ float RL(float x, int i) {
    return __uint_as_float((u32)__builtin_amdgcn_readlane((int)__float_as_uint(x), i));
}

// wave-level dtype detection (deterministic, barrier-free)
static __device__ __forceinline__ int detect_bf(const void* tr, int lane) {
    const u16* p = (const u16*)tr;
    int cnt = 0;
    for (int i = lane; i < 256; i += 64) {
        u16 v = p[2 * i];
        int e = (v >> 7) & 0xFF;
        if ((e >= 100 && e <= 141) || (v & 0x7FFFu) == 0) cnt++;
    }
    #pragma unroll
    for (int d = 1; d < 64; d <<= 1) cnt += __shfl_xor(cnt, d, 64);
    return cnt >= 192;
}
static __device__ __forceinline__ int detect_mm(const void* xmv, int lane) {
    const u32* xm = (const u32*)xmv;
    int anyBig = 0, oddNZ = 0;
    for (int i = lane; i < 1024; i += 64) {
        u32 w = xm[i];
        if (w & ~1u) anyBig = 1;
        if ((i & 1) && w) oddNZ = 1;
    }
    #pragma unroll
    for (int d = 1; d < 64; d <<= 1) {
        anyBig |= __shfl_xor(anyBig, d, 64);
        oddNZ  |= __shfl_xor(oddNZ, d, 64);
    }
    return anyBig ? 0 : (oddNZ ? 1 : 2);
}

__constant__ float cBB[9] = {-0.525f, 1.363f, 0.f,  0.f, 0.f, 0.f,  1.526f, 0.f, 0.f};

// u32 DPP min step (VALU pipe; d2>=0 -> f32 bit order == u32 order)
#define DPP_UMIN(var, CTRL) \
    { u32 o_ = (u32)__builtin_amdgcn_update_dpp((int)(var), (int)(var), CTRL, 0xF, 0xF, false); \
      (var) = (o_ < (var)) ? o_ : (var); }
#define DPP_UMIN_ALL(var) \
    DPP_UMIN(var, 0x111) DPP_UMIN(var, 0x112) DPP_UMIN(var, 0x114) \
    DPP_UMIN(var, 0x118) DPP_UMIN(var, 0x142) DPP_UMIN(var, 0x143)

// f32 add-reduce over 8-lane group via DPP (bit-identical to shfl_xor 1/2/4 tree)
#define DPP_ADD8(part) \
    part += __uint_as_float((u32)__builtin_amdgcn_update_dpp( \
        (int)__float_as_uint(part), (int)__float_as_uint(part), 0xB1, 0xF, 0xF, false)); \
    part += __uint_as_float((u32)__builtin_amdgcn_update_dpp( \
        (int)__float_as_uint(part), (int)__float_as_uint(part), 0x4E, 0xF, 0xF, false)); \
    part += __uint_as_float((u32)__builtin_amdgcn_update_dpp( \
        (int)__float_as_uint(part), (int)__float_as_uint(part), 0x141, 0xF, 0xF, false));

// ====== kernel 1: fused knn+prep — independent sections co-scheduled in one launch =========
// [0,2048): kNN (block 0 publishes flag)  [2048,4096): node (wave/node, barrier-free)
// [4096,4608): ptab (2 rows/block)        [4608,4616): weight-convert
__global__ __launch_bounds__(256) void knn_prep_kernel(
    const void* __restrict__ rots, const void* __restrict__ trans,
    const void* __restrict__ node, const void* __restrict__ xm,
    const void* __restrict__ nm,
    const void* __restrict__ Wa, const void* __restrict__ av,
    const void* __restrict__ Wv, const void* __restrict__ Wo,
    const void* __restrict__ Wg, const void* __restrict__ W2,
    int* __restrict__ flag, int* __restrict__ srcArr,
    float* __restrict__ hsrc, float* __restrict__ htgt,
    float* __restrict__ ptab, float* __restrict__ V,
    float* __restrict__ c_wrb, float* __restrict__ c_av,
    float* __restrict__ c_Wo, float* __restrict__ c_Wg, float* __restrict__ c_W2)
{
    __shared__ float sX[L_], sY[L_], sZ[L_];
    __shared__ int flagS[1];
    const int bid = blockIdx.x, tid = threadIdx.x;
    const int lane = tid & 63, wid = tid >> 6;

    if (bid < 2048) {
        // ---------------- kNN ----------------
        if (wid == 0) {
            int bf = detect_bf(trans, lane);
            if (bid == 0) {                 // publish flags for logits/agg kernels
                int mm = detect_mm(xm, lane);
                if (lane == 0) { flag[0] = bf; flag[1] = mm; }
            }
            if (lane == 0) flagS[0] = bf;
        }
        __syncthreads();
        const int bf = flagS[0];
        const int t0 = bid * 4;
        const int base = (t0 >> 9) << 9;
        if (bf) {
            const u16* tp = (const u16*)trans;
            for (int i = tid; i < L_; i += 256) {
                sX[i] = bfu16(tp[(base + i) * 3 + 0]);
                sY[i] = bfu16(tp[(base + i) * 3 + 1]);
                sZ[i] = bfu16(tp[(base + i) * 3 + 2]);
            }
        } else {
            const float* tp = (const float*)trans;
            for (int i = tid; i < L_; i += 256) {
                sX[i] = tp[(base + i) * 3 + 0];
                sY[i] = tp[(base + i) * 3 + 1];
                sZ[i] = tp[(base + i) * 3 + 2];
            }
        }
        __syncthreads();

        const int t = t0 + wid;
        const int l = t & 511;
        const float tx = sX[l], ty = sY[l], tz = sZ[l];

        u32 d2b[8];              // f32 bits of d2 (non-negative -> u32-order preserving)
        #pragma unroll
        for (int i = 0; i < 8; ++i) {
            int j = lane + (i << 6);
            // match numpy: ((dx*dx + dy*dy) + dz*dz), no FMA contraction
            float dx = __fsub_rn(tx, sX[j]);
            float dy = __fsub_rn(ty, sY[j]);
            float dz = __fsub_rn(tz, sZ[j]);
            float d2 = __fadd_rn(__fadd_rn(__fmul_rn(dx, dx), __fmul_rn(dy, dy)), __fmul_rn(dz, dz));
            if (j == l) d2 = __fadd_rn(d2, 1e9f);
            d2b[i] = __float_as_uint(d2);
        }

        int myres = 0;
        for (int k = 0; k < K_; ++k) {
            u32 bb = d2b[0]; int bs = 0;
            #pragma unroll
            for (int i = 1; i < 8; ++i)
                if (d2b[i] < bb) { bb = d2b[i]; bs = i; }
            u32 m = bb;
            DPP_UMIN_ALL(m)
            u32 gbits = (u32)__builtin_amdgcn_readlane((int)m, 63);
            u64 mask = __ballot(bb == gbits);
            u32 gidx;
            if (__popcll(mask) == 1) {
                int wl = __ffsll((long long)mask) - 1;
                gidx = (u32)__builtin_amdgcn_readlane((int)((bs << 6) | lane), wl);
            } else {
                u32 cand = (bb == gbits) ? (u32)((bs << 6) | lane) : 0xFFFFFFFFu;
                DPP_UMIN_ALL(cand)
                gidx = (u32)__builtin_amdgcn_readlane((int)cand, 63);
            }
            if (lane == (u32)k) myres = (int)(gidx & 511u);
            if ((gidx & 63u) == (u32)lane) {
                int ws = (int)(gidx >> 6);
                #pragma unroll
                for (int i = 0; i < 8; ++i)
                    if (ws == i) d2b[i] = 0xFFFFFFFFu;
            }
        }
        if (lane < K_) srcArr[t * K_ + lane] = base + myres;

    } else if (bid < 4096) {
        // ---------------- node: wave wid owns node n (per-wave detect, no barriers) --------
        const int n = (bid - 2048) * 4 + wid;
        const int bf = detect_bf(trans, lane);
        const int mm = detect_mm(xm, lane);

        float eA, eB, eC = 0.f;
        {
            int s = lane;                       // 0..63
            int r = s / 35, c = s - r * 35;
            if (c < H_)      eA = ldf(node, n * 128 + r * 32 + c, bf);
            else if (r == 0) eA = (c == 34) ? ((ldmask(nm, n, mm) && !ldmask(xm, n, mm)) ? 1.f : 0.f) : 0.f;
            else {
                int i = r - 1, a = c - 32;
                eA = ldf(rots, n*9 + i*3 + 0, bf) * cBB[a*3 + 0]
                   + ldf(rots, n*9 + i*3 + 1, bf) * cBB[a*3 + 1]
                   + ldf(rots, n*9 + i*3 + 2, bf) * cBB[a*3 + 2];
            }
            s = lane + 64;                      // 64..127
            r = s / 35; c = s - r * 35;
            if (c < H_)      eB = ldf(node, n * 128 + r * 32 + c, bf);
            else {
                int i = r - 1, a = c - 32;      // r>=1 always here
                eB = ldf(rots, n*9 + i*3 + 0, bf) * cBB[a*3 + 0]
                   + ldf(rots, n*9 + i*3 + 1, bf) * cBB[a*3 + 1]
                   + ldf(rots, n*9 + i*3 + 2, bf) * cBB[a*3 + 2];
            }
            if (lane < 12) {
                s = lane + 128;                 // 128..139
                r = s / 35; c = s - r * 35;
                if (c < H_)      eC = ldf(node, n * 128 + r * 32 + c, bf);
                else {
                    int i = r - 1, a = c - 32;
                    eC = ldf(rots, n*9 + i*3 + 0, bf) * cBB[a*3 + 0]
                       + ldf(rots, n*9 + i*3 + 1, bf) * cBB[a*3 + 1]
                       + ldf(rots, n*9 + i*3 + 2, bf) * cBB[a*3 + 2];
                }
            }
        }

        float a0 = 0.f, a1 = 0.f, b0 = 0.f, b1 = 0.f;
        float v0 = 0.f, v1 = 0.f, v2 = 0.f, v3 = 0.f;
        if (bf) {
            const u16* wa = (const u16*)Wa;
            const u16* wv = (const u16*)Wv;
            #pragma unroll
            for (int i = 0; i < 35; ++i) {
                float ei = RL(eA, i);
                a0 = fmaf(ei, bfu16(wa[i * 128 + lane]),        a0);
                a1 = fmaf(ei, bfu16(wa[i * 128 + lane + 64]),   a1);
                b0 = fmaf(ei, bfu16(wa[(35 + i) * 128 + lane]),      b0);
                b1 = fmaf(ei, bfu16(wa[(35 + i) * 128 + lane + 64]), b1);
            }
            #pragma unroll
            for (int cp = 0; cp < 35; ++cp) {
                float w = bfu16(wv[cp * 64 + lane]);
                float e1 = (35 + cp < 64) ? RL(eA, 35 + cp) : RL(eB, cp - 29);
                float e3 = (cp < 23) ? RL(eB, 41 + cp) : RL(eC, cp - 23);
                v0 = fmaf(RL(eA, cp), w, v0);
                v1 = fmaf(e1, w, v1);
                v2 = fmaf(RL(eB, cp + 6), w, v2);
                v3 = fmaf(e3, w, v3);
            }
        } else {
            const float* wa = (const float*)Wa;
            const float* wv = (const float*)Wv;
            #pragma unroll
            for (int i = 0; i < 35; ++i) {
                float ei = RL(eA, i);
                a0 = fmaf(ei, wa[i * 128 + lane],        a0);
                a1 = fmaf(ei, wa[i * 128 + lane + 64],   a1);
                b0 = fmaf(ei, wa[(35 + i) * 128 + lane],      b0);
                b1 = fmaf(ei, wa[(35 + i) * 128 + lane + 64], b1);
            }
            #pragma unroll
            for (int cp = 0; cp < 35; ++cp) {
                float w = wv[cp * 64 + lane];
                float e1 = (35 + cp < 64) ? RL(eA, 35 + cp) : RL(eB, cp - 29);
                float e3 = (cp < 23) ? RL(eB, 41 + cp) : RL(eC, cp - 23);
                v0 = fmaf(RL(eA, cp), w, v0);
                v1 = fmaf(e1, w, v1);
                v2 = fmaf(RL(eB, cp + 6), w, v2);
                v3 = fmaf(e3, w, v3);
            }
        }
        hsrc[(size_t)n * 128 + lane]      = a0;
        hsrc[(size_t)n * 128 + lane + 64] = a1;
        htgt[(size_t)n * 128 + lane]      = b0;
        htgt[(size_t)n * 128 + lane + 64] = b1;
        float* vp = V + (size_t)n * 256 + lane;
        vp[0] = v0; vp[64] = v1; vp[128] = v2; vp[192] = v3;

    } else if (bid < 4608) {
        // ---------------- ptab: 2 rows per block (per-wave detect) ----------------
        const int bf = detect_bf(trans, lane);
        const int d   = (bid - 4096) * 2 + (tid >> 7);
        const int col = tid & 127;
        float dd = (float)(d - 512);
        float acc = 0.f;
        if (bf) {
            const u16* wa = (const u16*)Wa;
            #pragma unroll
            for (int q = 0; q < 8; ++q) {
                float fr = expf((float)(2 * q) * (-0.5756462732485115f)); // -ln(1e4)/16
                float ang = dd * fr;
                acc = fmaf(cosf(ang), bfu16(wa[(86 + q) * 128 + col]), acc);
                acc = fmaf(sinf(ang), bfu16(wa[(94 + q) * 128 + col]), acc);
            }
        } else {
            const float* wa = (const float*)Wa;
            #pragma unroll
            for (int q = 0; q < 8; ++q) {
                float fr = expf((float)(2 * q) * (-0.5756462732485115f));
                float ang = dd * fr;
                acc = fmaf(cosf(ang), wa[(86 + q) * 128 + col], acc);
                acc = fmaf(sinf(ang), wa[(94 + q) * 128 + col], acc);
            }
        }
        ptab[(size_t)d * 128 + col] = acc;

    } else {
        // ---------------- convert downstream weights (per-wave detect) ----------------
        const int bf = detect_bf(trans, lane);
        int g0 = (bid - 4608) * 256 + tid;
        for (int i = g0; i < 6272; i += 2048) {
            if      (i < 2048) c_wrb[i]        = ldf(Wa, 70 * 128 + i, bf);
            else if (i < 2176) c_av[i - 2048]  = ldf(av, i - 2048, bf);
            else if (i < 4224) c_Wo[i - 2176]  = ldf(Wo, i - 2176, bf);
            else if (i < 5248) c_Wg[i - 4224]  = ldf(Wg, i - 4224, bf);
            else               c_W2[i - 5248]  = ldf(W2, i - 5248, bf);
        }
    }
}

// =============== kernel 2: per-edge logits (E-parallel, 32 edges/wave, pk-f32 GEMV) ==========
__global__ __launch_bounds__(128) void logits_kernel(
    const void* __restrict__ trans, const int* __restrict__ srcArr,
    const float* __restrict__ hsrc, const float* __restrict__ htgt,
    const float* __restrict__ ptab,
    const float* __restrict__ c_wrb, const float* __restrict__ c_av,
    const int* __restrict__ flag, float* __restrict__ logitsw)
{
    __shared__ float rbfS[2][32][20];   // pad 20 -> float4 rows
    __shared__ int   srcS[2][32];
    __shared__ int   tgtS[2][32];
    __shared__ int   dS[2][32];         // d | (invalid << 16)
    __shared__ float lgS[2][256];       // staged logits for coalesced flush
    const int tid = threadIdx.x, wid = tid >> 6, lane = tid & 63;
    const int bf = flag[0];

    const f2v* cw = (const f2v*)c_wrb;
    const f2v w0 = cw[0*64+lane],  w1 = cw[1*64+lane],  w2 = cw[2*64+lane],  w3 = cw[3*64+lane];
    const f2v w4 = cw[4*64+lane],  w5 = cw[5*64+lane],  w6 = cw[6*64+lane],  w7 = cw[7*64+lane];
    const f2v w8 = cw[8*64+lane],  w9 = cw[9*64+lane],  wA = cw[10*64+lane], wB = cw[11*64+lane];
    const f2v wC = cw[12*64+lane], wD = cw[13*64+lane], wE = cw[14*64+lane], wF = cw[15*64+lane];
    const f2v avv = ((const f2v*)c_av)[lane];

    const int e0 = (blockIdx.x * 2 + wid) * 32;

    // ---- phase A: lane pairs share an edge; each computes 8 of 16 rbf exps ----
    {
        const int el  = lane & 31;
        const int e   = e0 + el;
        const int tgt = e / K_;
        int src = srcArr[e];
        src = (src < 0) ? 0 : ((src >= N_) ? (N_ - 1) : src);
        float vx = ldf(trans, src*3+0, bf) - ldf(trans, tgt*3+0, bf);
        float vy = ldf(trans, src*3+1, bf) - ldf(trans, tgt*3+1, bf);
        float vz = ldf(trans, src*3+2, bf) - ldf(trans, tgt*3+2, bf);
        float dist = sqrtf(vx*vx + vy*vy + vz*vz);
        bool valid = isfinite(dist) && (dist > 1e-3f);
        int d = src - tgt + 512;
        d = (d < 0) ? 0 : ((d > 1023) ? 1023 : d);
        if (lane < 32) {
            srcS[wid][el] = src;
            tgtS[wid][el] = tgt;
            dS[wid][el]   = d | (valid ? 0 : (1 << 16));
        }
        const int jb = (lane >> 5) * 8;
        #pragma unroll
        for (int j = 0; j < 8; ++j) {
            float tt = (dist - (float)(jb + j) * (20.f/15.f)) * 0.8f;
            rbfS[wid][el][jb + j] = __expf(-tt * tt);
        }
    }
    __syncthreads();

    // ---- phase B: wave sweeps its 32 edges (pk-f32) ----
    const float* hsL = hsrc + (lane << 1);
    const float* htL = htgt + (lane << 1);
    const float* ptL = ptab + (lane << 1);
    #pragma unroll 2
    for (int q = 0; q < 32; ++q) {
        const int src = srcS[wid][q];
        const int tgt = tgtS[wid][q];
        const int dm  = dS[wid][q];
        const int d   = dm & 0xFFFF;
        const bool valid = (dm >> 16) == 0;

        f2v hs = *(const f2v*)(hsL + (src << 7));
        f2v ht = *(const f2v*)(htL + (tgt << 7));
        f2v pt = *(const f2v*)(ptL + (d << 7));
        f2v acc = (hs + ht) + pt;
        const float4* rp = (const float4*)(&rbfS[wid][q][0]);
        float4 ra = rp[0], rb = rp[1], rc = rp[2], rd = rp[3];   // broadcast reads
        acc = __builtin_elementwise_fma(splat2(ra.x), w0, acc);
        acc = __builtin_elementwise_fma(splat2(ra.y), w1, acc);
        acc = __builtin_elementwise_fma(splat2(ra.z), w2, acc);
        acc = __builtin_elementwise_fma(splat2(ra.w), w3, acc);
        acc = __builtin_elementwise_fma(splat2(rb.x), w4, acc);
        acc = __builtin_elementwise_fma(splat2(rb.y), w5, acc);
        acc = __builtin_elementwise_fma(splat2(rb.z), w6, acc);
        acc = __builtin_elementwise_fma(splat2(rb.w), w7, acc);
        acc = __builtin_elementwise_fma(splat2(rc.x), w8, acc);
        acc = __builtin_elementwise_fma(splat2(rc.y), w9, acc);
        acc = __builtin_elementwise_fma(splat2(rc.z), wA, acc);
        acc = __builtin_elementwise_fma(splat2(rc.w), wB, acc);
        acc = __builtin_elementwise_fma(splat2(rd.x), wC, acc);
        acc = __builtin_elementwise_fma(splat2(rd.y), wD, acc);
        acc = __builtin_elementwise_fma(splat2(rd.z), wE, acc);
        acc = __builtin_elementwise_fma(splat2(rd.w), wF, acc);
        float part = fsilu(acc.x) * avv.x + fsilu(acc.y) * avv.y;
        DPP_ADD8(part)
        float lg = (part >= 0.f) ? part : 0.2f * part;
        if (!valid) lg = -1e9f;
        lg = (fabsf(lg) < 1e30f) ? lg : -1e9f;
        if ((lane & 7) == 0) lgS[wid][q * 8 + (lane >> 3)] = lg;
    }
    __syncthreads();
    {   // coalesced flush: 256 floats per wave = 1 float4 per lane
        float4* dst = (float4*)(logitsw + (size_t)e0 * 8);
        dst[lane] = ((const float4*)lgS[wid])[lane];
    }
}

// =============== kernel 3: softmax (dedup) + batched V sum + epilogue =====================
__global__ __launch_bounds__(256) void agg_out_kernel(
    const float* __restrict__ V, const int* __restrict__ srcArr,
    const float* __restrict__ logitsw,
    const float* __restrict__ Wo, const float* __restrict__ Wg,
    const float* __restrict__ W2,
    const int* __restrict__ flag, void* __restrict__ outv)
{
    __shared__ float lgS[240];          // logits -> unnormalized exp weights
    __shared__ float invS[8];
    __shared__ int   voffS[K_];
    __shared__ float aggS[256];
    __shared__ float ybuf[128];
    __shared__ float gbuf[32];
    const int bid = blockIdx.x, tid = threadIdx.x;
    const int t   = ((bid & 7) << 10) | (bid >> 3);   // XCD-locality swizzle
    const int bf = flag[0];

    if (tid < 240) lgS[tid] = logitsw[(size_t)t * 240 + tid];
    if (tid < K_) {
        int s = srcArr[t * K_ + tid];
        s = (s < 0) ? 0 : ((s >= N_) ? (N_ - 1) : s);
        voffS[tid] = s << 8;
    }
    __syncthreads();

    // softmax numerators once per (k,h): thread h handles head h
    if (tid < 8) {
        float mx = -1e30f;
        #pragma unroll
        for (int k = 0; k < K_; ++k) mx = fmaxf(mx, lgS[k * 8 + tid]);
        float den = 0.f;
        #pragma unroll
        for (int k = 0; k < K_; ++k) {
            float l = lgS[k * 8 + tid];
            float e = (l > -1e8f) ? __expf(l - mx) : 0.f;
            lgS[k * 8 + tid] = e; den += e;
        }
        invS[tid] = 1.f / (den + 1e-9f);
    }
    __syncthreads();

    // batched V gather (explicit array -> 30 outstanding loads), then pure FMA chain
    {
        const int h = (tid & 63) >> 3;
        float vv[K_];
        #pragma unroll
        for (int k = 0; k < K_; ++k) vv[k] = V[voffS[k] + tid];
        float acc = 0.f;
        #pragma unroll
        for (int k = 0; k < K_; ++k) acc = fmaf(lgS[k * 8 + h], vv[k], acc);
        aggS[tid] = acc * invS[h];
    }
    __syncthreads();

    // epilogue: y = agg @ W_o ; gate = silu(y0 @ W_g) ; out = (y*gate) @ W_2
    if (tid < 128) {
        int rr = tid >> 5, o = tid & 31;
        float y = 0.f;
        #pragma unroll
        for (int c = 0; c < 64; ++c) y = fmaf(aggS[rr * 64 + c], Wo[c * 32 + o], y);
        ybuf[tid] = y;
    }
    __syncthreads();
    if (tid < 32) {
        float g = 0.f;
        #pragma unroll
        for (int o = 0; o < 32; ++o) g = fmaf(ybuf[o], Wg[o * 32 + tid], g);
        gbuf[tid] = fsilu(g);
    }
    __syncthreads();
    if (tid < 128) {
        int rr = tid >> 5, hh = tid & 31;
        float o = 0.f;
        #pragma unroll
        for (int g = 0; g < 32; ++g) o = fmaf(ybuf[rr * 32 + g] * gbuf[g], W2[g * 32 + hh], o);
        o = (fabsf(o) < 1e30f) ? o : 0.f;
        size_t idx = (size_t)t * 128 + tid;
        if (bf) ((u16*)outv)[idx] = f2bf(o);
        else    ((float*)outv)[idx] = o;
    }
}

extern "C" void kernel_launch(void* const* d_in, const int* in_sizes, int n_in,
                              void* d_out, int out_size, void* d_ws, size_t ws_size,
                              hipStream_t stream)
{
    const void* rots         = d_in[0];
    const void* trans        = d_in[1];
    const void* node_emb     = d_in[2];
    /* d_in[3] = batch (unused; chains contiguous) */
    const void* x_mask       = d_in[4];
    const void* noising_mask = d_in[5];
    const void* Wa           = d_in[6];
    const void* avec         = d_in[7];
    const void* Wv           = d_in[8];
    const void* Wo           = d_in[9];
    const void* Wg           = d_in[10];
    const void* W2           = d_in[11];

    char* ws = (char*)d_ws;
    int*   flag    = (int*)  (ws + 0);            //        64
    int*   srcArr  = (int*)  (ws + 64);           //   983,040
    float* hsrc    = (float*)(ws + 983104);       // 4,194,304
    float* htgt    = (float*)(ws + 5177408);      // 4,194,304
    float* ptab    = (float*)(ws + 9371712);      //   524,288
    float* V       = (float*)(ws + 9896000);      // 8,388,608
    float* c_wrb   = (float*)(ws + 18284608);     //     8,192
    float* c_av    = (float*)(ws + 18292800);     //       512
    float* c_Wo    = (float*)(ws + 18293312);     //     8,192
    float* c_Wg    = (float*)(ws + 18301504);     //     4,096
    float* c_W2    = (float*)(ws + 18305600);     //     4,096
    float* logitsw = (float*)(ws + 18309696);     // 7,864,320  (end ~26.2 MB)

    hipLaunchKernelGGL(knn_prep_kernel, dim3(2048 + 2048 + 512 + 8), dim3(256), 0, stream,
                       rots, trans, node_emb, x_mask, noising_mask,
                       Wa, avec, Wv, Wo, Wg, W2,
                       flag, srcArr, hsrc, htgt, ptab, V,
                       c_wrb, c_av, c_Wo, c_Wg, c_W2);
    hipLaunchKernelGGL(logits_kernel, dim3(E_/64), dim3(128), 0, stream,
                       trans, srcArr, hsrc, htgt, ptab, c_wrb, c_av, flag, logitsw);
    hipLaunchKernelGGL(agg_out_kernel, dim3(N_), dim3(256), 0, stream,
                       V, srcArr, logitsw, c_Wo, c_Wg, c_W2, flag, d_out);
}

// Round 19
// 201.804 us; speedup vs baseline: 1.0242x; 1.0242x over previous
//
#include <hip/hip_runtime.h>
#include <cstdint>

#define B_ 16
#define L_ 512
#define N_ 8192
#define K_ 30
#define E_ (N_*K_)
#define H_ 32
#define C_ 35

typedef uint16_t u16;
typedef uint32_t u32;
typedef unsigned long long u64;
typedef float f2v __attribute__((ext_vector_type(2)));

static __device__ __forceinline__ f2v splat2(float x) { f2v v; v.x = x; v.y = x; return v; }

// adaptive float load: bf16 (u16<<16) or fp32
static __device__ __forceinline__ float ldf(const void* p, int i, int bf) {
    return bf ? __uint_as_float(((u32)((const u16*)p)[i]) << 16)
              : ((const float*)p)[i];
}
static __device__ __forceinline__ float bfu16(u16 x) {
    return __uint_as_float(((u32)x) << 16);
}
// mask load: mode 0 = u8 bool, 1 = int32, 2 = int64 (little-endian low word)
static __device__ __forceinline__ int ldmask(const void* p, int i, int mode) {
    if (mode == 0) return ((const unsigned char*)p)[i] != 0;
    if (mode == 2) return ((const u32*)p)[2*i] != 0;
    return ((const u32*)p)[i] != 0;
}
// f32 -> bf16 RNE
static __device__ __forceinline__ u16 f2bf(float f) {
    u32 x = __float_as_uint(f);
    u32 r = x + 0x7FFFu + ((x >> 16) & 1u);
    return (u16)(r >> 16);
}
// fast silu (~1e-7 rel err; threshold 4.3e-3)
static __device__ __forceinline__ float fsilu(float x) {
    return x * __builtin_amdgcn_rcpf(1.f + __expf(-x));
}
// wave-uniform-index register broadcast (SGPR result -> free fmaf operand)
static __device__ __forceinline__ float RL(float x, int i) {
    return __uint_as_float((u32)__builtin_amdgcn_readlane((int)__float_as_uint(x), i));
}

// wave-level dtype detection (deterministic)
static __device__ __forceinline__ int detect_bf(const void* tr, int lane) {
    const u16* p = (const u16*)tr;
    int cnt = 0;
    for (int i = lane; i < 256; i += 64) {
        u16 v = p[2 * i];
        int e = (v >> 7) & 0xFF;
        if ((e >= 100 && e <= 141) || (v & 0x7FFFu) == 0) cnt++;
    }
    #pragma unroll
    for (int d = 1; d < 64; d <<= 1) cnt += __shfl_xor(cnt, d, 64);
    return cnt >= 192;
}
static __device__ __forceinline__ int detect_mm(const void* xmv, int lane) {
    const u32* xm = (const u32*)xmv;
    int anyBig = 0, oddNZ = 0;
    for (int i = lane; i < 1024; i += 64) {
        u32 w = xm[i];
        if (w & ~1u) anyBig = 1;
        if ((i & 1) && w) oddNZ = 1;
    }
    #pragma unroll
    for (int d = 1; d < 64; d <<= 1) {
        anyBig |= __shfl_xor(anyBig, d, 64);
        oddNZ  |= __shfl_xor(oddNZ, d, 64);
    }
    return anyBig ? 0 : (oddNZ ? 1 : 2);
}

__constant__ float cBB[9] = {-0.525f, 1.363f, 0.f,  0.f, 0.f, 0.f,  1.526f, 0.f, 0.f};

// u32 DPP min step (VALU pipe; d2>=0 -> f32 bit order == u32 order)
#define DPP_UMIN(var, CTRL) \
    { u32 o_ = (u32)__builtin_amdgcn_update_dpp((int)(var), (int)(var), CTRL, 0xF, 0xF, false); \
      (var) = (o_ < (var)) ? o_ : (var); }
#define DPP_UMIN_ALL(var) \
    DPP_UMIN(var, 0x111) DPP_UMIN(var, 0x112) DPP_UMIN(var, 0x114) \
    DPP_UMIN(var, 0x118) DPP_UMIN(var, 0x142) DPP_UMIN(var, 0x143)

// f32 add-reduce over 8-lane group via DPP (bit-identical to shfl_xor 1/2/4 tree)
#define DPP_ADD8(part) \
    part += __uint_as_float((u32)__builtin_amdgcn_update_dpp( \
        (int)__float_as_uint(part), (int)__float_as_uint(part), 0xB1, 0xF, 0xF, false)); \
    part += __uint_as_float((u32)__builtin_amdgcn_update_dpp( \
        (int)__float_as_uint(part), (int)__float_as_uint(part), 0x4E, 0xF, 0xF, false)); \
    part += __uint_as_float((u32)__builtin_amdgcn_update_dpp( \
        (int)__float_as_uint(part), (int)__float_as_uint(part), 0x141, 0xF, 0xF, false));

// =============== kernel 1: per-chain kNN (+ block 0 publishes dtype flags) =================
__global__ __launch_bounds__(256) void knn_kernel(const void* __restrict__ trans,
                                                  const void* __restrict__ xm,
                                                  int* __restrict__ flag,
                                                  int* __restrict__ srcArr)
{
    __shared__ float sX[L_], sY[L_], sZ[L_];
    __shared__ int flagS[1];
    const int bid = blockIdx.x, tid = threadIdx.x;
    const int lane = tid & 63, wid = tid >> 6;

    if (wid == 0) {
        int bf = detect_bf(trans, lane);
        if (bid == 0) {                     // publish flags for downstream kernels
            int mm = detect_mm(xm, lane);
            if (lane == 0) { flag[0] = bf; flag[1] = mm; }
        }
        if (lane == 0) flagS[0] = bf;
    }
    __syncthreads();
    const int bf = flagS[0];
    const int t0 = bid * 4;
    const int base = (t0 >> 9) << 9;
    if (bf) {
        const u16* tp = (const u16*)trans;
        for (int i = tid; i < L_; i += 256) {
            sX[i] = bfu16(tp[(base + i) * 3 + 0]);
            sY[i] = bfu16(tp[(base + i) * 3 + 1]);
            sZ[i] = bfu16(tp[(base + i) * 3 + 2]);
        }
    } else {
        const float* tp = (const float*)trans;
        for (int i = tid; i < L_; i += 256) {
            sX[i] = tp[(base + i) * 3 + 0];
            sY[i] = tp[(base + i) * 3 + 1];
            sZ[i] = tp[(base + i) * 3 + 2];
        }
    }
    __syncthreads();

    const int t = t0 + wid;
    const int l = t & 511;
    const float tx = sX[l], ty = sY[l], tz = sZ[l];

    u32 d2b[8];              // f32 bits of d2 (non-negative -> u32-order preserving)
    #pragma unroll
    for (int i = 0; i < 8; ++i) {
        int j = lane + (i << 6);
        // match numpy: ((dx*dx + dy*dy) + dz*dz), no FMA contraction
        float dx = __fsub_rn(tx, sX[j]);
        float dy = __fsub_rn(ty, sY[j]);
        float dz = __fsub_rn(tz, sZ[j]);
        float d2 = __fadd_rn(__fadd_rn(__fmul_rn(dx, dx), __fmul_rn(dy, dy)), __fmul_rn(dz, dz));
        if (j == l) d2 = __fadd_rn(d2, 1e9f);
        d2b[i] = __float_as_uint(d2);
    }

    int myres = 0;
    for (int k = 0; k < K_; ++k) {
        u32 bb = d2b[0]; int bs = 0;
        #pragma unroll
        for (int i = 1; i < 8; ++i)
            if (d2b[i] < bb) { bb = d2b[i]; bs = i; }
        u32 m = bb;
        DPP_UMIN_ALL(m)
        u32 gbits = (u32)__builtin_amdgcn_readlane((int)m, 63);
        u64 mask = __ballot(bb == gbits);
        u32 gidx;
        if (__popcll(mask) == 1) {
            int wl = __ffsll((long long)mask) - 1;
            gidx = (u32)__builtin_amdgcn_readlane((int)((bs << 6) | lane), wl);
        } else {
            u32 cand = (bb == gbits) ? (u32)((bs << 6) | lane) : 0xFFFFFFFFu;
            DPP_UMIN_ALL(cand)
            gidx = (u32)__builtin_amdgcn_readlane((int)cand, 63);
        }
        if (lane == (u32)k) myres = (int)(gidx & 511u);
        if ((gidx & 63u) == (u32)lane) {
            int ws = (int)(gidx >> 6);
            #pragma unroll
            for (int i = 0; i < 8; ++i)
                if (ws == i) d2b[i] = 0xFFFFFFFFu;
        }
    }
    if (lane < K_) srcArr[t * K_ + lane] = base + myres;
}

// =============== kernel 2: prep (node | ptab | conv) — barrier-free, LDS-free node ==========
__global__ __launch_bounds__(256) void prep_kernel(
    const void* __restrict__ rots, const void* __restrict__ node,
    const void* __restrict__ xm, const void* __restrict__ nm,
    const void* __restrict__ Wa, const void* __restrict__ av,
    const void* __restrict__ Wv, const void* __restrict__ Wo,
    const void* __restrict__ Wg, const void* __restrict__ W2,
    const int* __restrict__ flag,
    float* __restrict__ hsrc, float* __restrict__ htgt,
    float* __restrict__ ptab, float* __restrict__ V,
    float* __restrict__ c_wrb, float* __restrict__ c_av,
    float* __restrict__ c_Wo, float* __restrict__ c_Wg, float* __restrict__ c_W2)
{
    const int bid = blockIdx.x, tid = threadIdx.x;
    const int lane = tid & 63, wid = tid >> 6;
    const int bf = flag[0], mm = flag[1];

    if (bid < 2048) {
        // ---------------- node: wave wid owns node n ----------------
        const int n = bid * 4 + wid;

        float eA, eB, eC = 0.f;
        {
            int s = lane;                       // 0..63
            int r = s / 35, c = s - r * 35;
            if (c < H_)      eA = ldf(node, n * 128 + r * 32 + c, bf);
            else if (r == 0) eA = (c == 34) ? ((ldmask(nm, n, mm) && !ldmask(xm, n, mm)) ? 1.f : 0.f) : 0.f;
            else {
                int i = r - 1, a = c - 32;
                eA = ldf(rots, n*9 + i*3 + 0, bf) * cBB[a*3 + 0]
                   + ldf(rots, n*9 + i*3 + 1, bf) * cBB[a*3 + 1]
                   + ldf(rots, n*9 + i*3 + 2, bf) * cBB[a*3 + 2];
            }
            s = lane + 64;                      // 64..127
            r = s / 35; c = s - r * 35;
            if (c < H_)      eB = ldf(node, n * 128 + r * 32 + c, bf);
            else {
                int i = r - 1, a = c - 32;      // r>=1 always here
                eB = ldf(rots, n*9 + i*3 + 0, bf) * cBB[a*3 + 0]
                   + ldf(rots, n*9 + i*3 + 1, bf) * cBB[a*3 + 1]
                   + ldf(rots, n*9 + i*3 + 2, bf) * cBB[a*3 + 2];
            }
            if (lane < 12) {
                s = lane + 128;                 // 128..139
                r = s / 35; c = s - r * 35;
                if (c < H_)      eC = ldf(node, n * 128 + r * 32 + c, bf);
                else {
                    int i = r - 1, a = c - 32;
                    eC = ldf(rots, n*9 + i*3 + 0, bf) * cBB[a*3 + 0]
                       + ldf(rots, n*9 + i*3 + 1, bf) * cBB[a*3 + 1]
                       + ldf(rots, n*9 + i*3 + 2, bf) * cBB[a*3 + 2];
                }
            }
        }

        float a0 = 0.f, a1 = 0.f, b0 = 0.f, b1 = 0.f;
        float v0 = 0.f, v1 = 0.f, v2 = 0.f, v3 = 0.f;
        if (bf) {
            const u16* wa = (const u16*)Wa;
            const u16* wv = (const u16*)Wv;
            #pragma unroll
            for (int i = 0; i < 35; ++i) {
                float ei = RL(eA, i);
                a0 = fmaf(ei, bfu16(wa[i * 128 + lane]),        a0);
                a1 = fmaf(ei, bfu16(wa[i * 128 + lane + 64]),   a1);
                b0 = fmaf(ei, bfu16(wa[(35 + i) * 128 + lane]),      b0);
                b1 = fmaf(ei, bfu16(wa[(35 + i) * 128 + lane + 64]), b1);
            }
            #pragma unroll
            for (int cp = 0; cp < 35; ++cp) {
                float w = bfu16(wv[cp * 64 + lane]);
                float e1 = (35 + cp < 64) ? RL(eA, 35 + cp) : RL(eB, cp - 29);
                float e3 = (cp < 23) ? RL(eB, 41 + cp) : RL(eC, cp - 23);
                v0 = fmaf(RL(eA, cp), w, v0);
                v1 = fmaf(e1, w, v1);
                v2 = fmaf(RL(eB, cp + 6), w, v2);
                v3 = fmaf(e3, w, v3);
            }
        } else {
            const float* wa = (const float*)Wa;
            const float* wv = (const float*)Wv;
            #pragma unroll
            for (int i = 0; i < 35; ++i) {
                float ei = RL(eA, i);
                a0 = fmaf(ei, wa[i * 128 + lane],        a0);
                a1 = fmaf(ei, wa[i * 128 + lane + 64],   a1);
                b0 = fmaf(ei, wa[(35 + i) * 128 + lane],      b0);
                b1 = fmaf(ei, wa[(35 + i) * 128 + lane + 64], b1);
            }
            #pragma unroll
            for (int cp = 0; cp < 35; ++cp) {
                float w = wv[cp * 64 + lane];
                float e1 = (35 + cp < 64) ? RL(eA, 35 + cp) : RL(eB, cp - 29);
                float e3 = (cp < 23) ? RL(eB, 41 + cp) : RL(eC, cp - 23);
                v0 = fmaf(RL(eA, cp), w, v0);
                v1 = fmaf(e1, w, v1);
                v2 = fmaf(RL(eB, cp + 6), w, v2);
                v3 = fmaf(e3, w, v3);
            }
        }
        hsrc[(size_t)n * 128 + lane]      = a0;
        hsrc[(size_t)n * 128 + lane + 64] = a1;
        htgt[(size_t)n * 128 + lane]      = b0;
        htgt[(size_t)n * 128 + lane + 64] = b1;
        float* vp = V + (size_t)n * 256 + lane;
        vp[0] = v0; vp[64] = v1; vp[128] = v2; vp[192] = v3;

    } else if (bid < 2560) {
        // ---------------- ptab: 2 rows per block ----------------
        const int d   = (bid - 2048) * 2 + (tid >> 7);
        const int col = tid & 127;
        float dd = (float)(d - 512);
        float acc = 0.f;
        if (bf) {
            const u16* wa = (const u16*)Wa;
            #pragma unroll
            for (int q = 0; q < 8; ++q) {
                float fr = expf((float)(2 * q) * (-0.5756462732485115f)); // -ln(1e4)/16
                float ang = dd * fr;
                acc = fmaf(cosf(ang), bfu16(wa[(86 + q) * 128 + col]), acc);
                acc = fmaf(sinf(ang), bfu16(wa[(94 + q) * 128 + col]), acc);
            }
        } else {
            const float* wa = (const float*)Wa;
            #pragma unroll
            for (int q = 0; q < 8; ++q) {
                float fr = expf((float)(2 * q) * (-0.5756462732485115f));
                float ang = dd * fr;
                acc = fmaf(cosf(ang), wa[(86 + q) * 128 + col], acc);
                acc = fmaf(sinf(ang), wa[(94 + q) * 128 + col], acc);
            }
        }
        ptab[(size_t)d * 128 + col] = acc;

    } else {
        // ---------------- convert K3/K4 weights ----------------
        int g0 = (bid - 2560) * 256 + tid;
        for (int i = g0; i < 6272; i += 2048) {
            if      (i < 2048) c_wrb[i]        = ldf(Wa, 70 * 128 + i, bf);
            else if (i < 2176) c_av[i - 2048]  = ldf(av, i - 2048, bf);
            else if (i < 4224) c_Wo[i - 2176]  = ldf(Wo, i - 2176, bf);
            else if (i < 5248) c_Wg[i - 4224]  = ldf(Wg, i - 4224, bf);
            else               c_W2[i - 5248]  = ldf(W2, i - 5248, bf);
        }
    }
}

// =============== kernel 3: per-edge logits (E-parallel, 32 edges/wave, pk-f32 GEMV) ==========
__global__ __launch_bounds__(128) void logits_kernel(
    const void* __restrict__ trans, const int* __restrict__ srcArr,
    const float* __restrict__ hsrc, const float* __restrict__ htgt,
    const float* __restrict__ ptab,
    const float* __restrict__ c_wrb, const float* __restrict__ c_av,
    const int* __restrict__ flag, float* __restrict__ logitsw)
{
    __shared__ float rbfS[2][32][20];   // pad 20 -> float4 rows
    __shared__ int   srcS[2][32];
    __shared__ int   tgtS[2][32];
    __shared__ int   dS[2][32];         // d | (invalid << 16)
    __shared__ float lgS[2][256];       // staged logits for coalesced flush
    const int tid = threadIdx.x, wid = tid >> 6, lane = tid & 63;
    const int bf = flag[0];

    const f2v* cw = (const f2v*)c_wrb;
    const f2v w0 = cw[0*64+lane],  w1 = cw[1*64+lane],  w2 = cw[2*64+lane],  w3 = cw[3*64+lane];
    const f2v w4 = cw[4*64+lane],  w5 = cw[5*64+lane],  w6 = cw[6*64+lane],  w7 = cw[7*64+lane];
    const f2v w8 = cw[8*64+lane],  w9 = cw[9*64+lane],  wA = cw[10*64+lane], wB = cw[11*64+lane];
    const f2v wC = cw[12*64+lane], wD = cw[13*64+lane], wE = cw[14*64+lane], wF = cw[15*64+lane];
    const f2v avv = ((const f2v*)c_av)[lane];

    const int e0 = (blockIdx.x * 2 + wid) * 32;

    // ---- phase A: lane pairs share an edge; each computes 8 of 16 rbf exps ----
    {
        const int el  = lane & 31;
        const int e   = e0 + el;
        const int tgt = e / K_;
        int src = srcArr[e];
        src = (src < 0) ? 0 : ((src >= N_) ? (N_ - 1) : src);
        float vx = ldf(trans, src*3+0, bf) - ldf(trans, tgt*3+0, bf);
        float vy = ldf(trans, src*3+1, bf) - ldf(trans, tgt*3+1, bf);
        float vz = ldf(trans, src*3+2, bf) - ldf(trans, tgt*3+2, bf);
        float dist = sqrtf(vx*vx + vy*vy + vz*vz);
        bool valid = isfinite(dist) && (dist > 1e-3f);
        int d = src - tgt + 512;
        d = (d < 0) ? 0 : ((d > 1023) ? 1023 : d);
        if (lane < 32) {
            srcS[wid][el] = src;
            tgtS[wid][el] = tgt;
            dS[wid][el]   = d | (valid ? 0 : (1 << 16));
        }
        const int jb = (lane >> 5) * 8;
        #pragma unroll
        for (int j = 0; j < 8; ++j) {
            float tt = (dist - (float)(jb + j) * (20.f/15.f)) * 0.8f;
            rbfS[wid][el][jb + j] = __expf(-tt * tt);
        }
    }
    __syncthreads();

    // ---- phase B: wave sweeps its 32 edges (pk-f32) ----
    const float* hsL = hsrc + (lane << 1);
    const float* htL = htgt + (lane << 1);
    const float* ptL = ptab + (lane << 1);
    #pragma unroll 2
    for (int q = 0; q < 32; ++q) {
        const int src = srcS[wid][q];
        const int tgt = tgtS[wid][q];
        const int dm  = dS[wid][q];
        const int d   = dm & 0xFFFF;
        const bool valid = (dm >> 16) == 0;

        f2v hs = *(const f2v*)(hsL + (src << 7));
        f2v ht = *(const f2v*)(htL + (tgt << 7));
        f2v pt = *(const f2v*)(ptL + (d << 7));
        f2v acc = (hs + ht) + pt;
        const float4* rp = (const float4*)(&rbfS[wid][q][0]);
        float4 ra = rp[0], rb = rp[1], rc = rp[2], rd = rp[3];   // broadcast reads
        acc = __builtin_elementwise_fma(splat2(ra.x), w0, acc);
        acc = __builtin_elementwise_fma(splat2(ra.y), w1, acc);
        acc = __builtin_elementwise_fma(splat2(ra.z), w2, acc);
        acc = __builtin_elementwise_fma(splat2(ra.w), w3, acc);
        acc = __builtin_elementwise_fma(splat2(rb.x), w4, acc);
        acc = __builtin_elementwise_fma(splat2(rb.y), w5, acc);
        acc = __builtin_elementwise_fma(splat2(rb.z), w6, acc);
        acc = __builtin_elementwise_fma(splat2(rb.w), w7, acc);
        acc = __builtin_elementwise_fma(splat2(rc.x), w8, acc);
        acc = __builtin_elementwise_fma(splat2(rc.y), w9, acc);
        acc = __builtin_elementwise_fma(splat2(rc.z), wA, acc);
        acc = __builtin_elementwise_fma(splat2(rc.w), wB, acc);
        acc = __builtin_elementwise_fma(splat2(rd.x), wC, acc);
        acc = __builtin_elementwise_fma(splat2(rd.y), wD, acc);
        acc = __builtin_elementwise_fma(splat2(rd.z), wE, acc);
        acc = __builtin_elementwise_fma(splat2(rd.w), wF, acc);
        float part = fsilu(acc.x) * avv.x + fsilu(acc.y) * avv.y;
        DPP_ADD8(part)
        float lg = (part >= 0.f) ? part : 0.2f * part;
        if (!valid) lg = -1e9f;
        lg = (fabsf(lg) < 1e30f) ? lg : -1e9f;
        if ((lane & 7) == 0) lgS[wid][q * 8 + (lane >> 3)] = lg;
    }
    __syncthreads();
    {   // coalesced flush: 256 floats per wave = 1 float4 per lane
        float4* dst = (float4*)(logitsw + (size_t)e0 * 8);
        dst[lane] = ((const float4*)lgS[wid])[lane];
    }
}

// =============== kernel 4: softmax (dedup) + batched V sum + epilogue =====================
__global__ __launch_bounds__(256) void agg_out_kernel(
    const float* __restrict__ V, const int* __restrict__ srcArr,
    const float* __restrict__ logitsw,
    const float* __restrict__ Wo, const float* __restrict__ Wg,
    const float* __restrict__ W2,
    const int* __restrict__ flag, void* __restrict__ outv)
{
    __shared__ float lgS[240];          // logits -> unnormalized exp weights
    __shared__ float invS[8];
    __shared__ int   voffS[K_];
    __shared__ float aggS[256];
    __shared__ float ybuf[128];
    __shared__ float gbuf[32];
    const int bid = blockIdx.x, tid = threadIdx.x;
    const int t   = ((bid & 7) << 10) | (bid >> 3);   // XCD-locality swizzle
    const int bf = flag[0];

    if (tid < 240) lgS[tid] = logitsw[(size_t)t * 240 + tid];
    if (tid < K_) {
        int s = srcArr[t * K_ + tid];
        s = (s < 0) ? 0 : ((s >= N_) ? (N_ - 1) : s);
        voffS[tid] = s << 8;
    }
    __syncthreads();

    // softmax numerators once per (k,h): thread h handles head h
    if (tid < 8) {
        float mx = -1e30f;
        #pragma unroll
        for (int k = 0; k < K_; ++k) mx = fmaxf(mx, lgS[k * 8 + tid]);
        float den = 0.f;
        #pragma unroll
        for (int k = 0; k < K_; ++k) {
            float l = lgS[k * 8 + tid];
            float e = (l > -1e8f) ? __expf(l - mx) : 0.f;
            lgS[k * 8 + tid] = e; den += e;
        }
        invS[tid] = 1.f / (den + 1e-9f);
    }
    __syncthreads();

    // batched V gather (explicit array -> 30 outstanding loads), then pure FMA chain
    {
        const int h = (tid & 63) >> 3;
        float vv[K_];
        #pragma unroll
        for (int k = 0; k < K_; ++k) vv[k] = V[voffS[k] + tid];
        float acc = 0.f;
        #pragma unroll
        for (int k = 0; k < K_; ++k) acc = fmaf(lgS[k * 8 + h], vv[k], acc);
        aggS[tid] = acc * invS[h];
    }
    __syncthreads();

    // epilogue: y = agg @ W_o ; gate = silu(y0 @ W_g) ; out = (y*gate) @ W_2
    if (tid < 128) {
        int rr = tid >> 5, o = tid & 31;
        float y = 0.f;
        #pragma unroll
        for (int c = 0; c < 64; ++c) y = fmaf(aggS[rr * 64 + c], Wo[c * 32 + o], y);
        ybuf[tid] = y;
    }
    __syncthreads();
    if (tid < 32) {
        float g = 0.f;
        #pragma unroll
        for (int o = 0; o < 32; ++o) g = fmaf(ybuf[o], Wg[o * 32 + tid], g);
        gbuf[tid] = fsilu(g);
    }
    __syncthreads();
    if (tid < 128) {
        int rr = tid >> 5, hh = tid & 31;
        float o = 0.f;
        #pragma unroll
        for (int g = 0; g < 32; ++g) o = fmaf(ybuf[rr * 32 + g] * gbuf[g], W2[g * 32 + hh], o);
        o = (fabsf(o) < 1e30f) ? o : 0.f;
        size_t idx = (size_t)t * 128 + tid;
        if (bf) ((u16*)outv)[idx] = f2bf(o);
        else    ((float*)outv)[idx] = o;
    }
}

extern "C" void kernel_launch(void* const* d_in, const int* in_sizes, int n_in,
                              void* d_out, int out_size, void* d_ws, size_t ws_size,
                              hipStream_t stream)
{
    const void* rots         = d_in[0];
    const void* trans        = d_in[1];
    const void* node_emb     = d_in[2];
    /* d_in[3] = batch (unused; chains contiguous) */
    const void* x_mask       = d_in[4];
    const void* noising_mask = d_in[5];
    const void* Wa           = d_in[6];
    const void* avec         = d_in[7];
    const void* Wv           = d_in[8];
    const void* Wo           = d_in[9];
    const void* Wg           = d_in[10];
    const void* W2           = d_in[11];

    char* ws = (char*)d_ws;
    int*   flag    = (int*)  (ws + 0);            //        64
    int*   srcArr  = (int*)  (ws + 64);           //   983,040
    float* hsrc    = (float*)(ws + 983104);       // 4,194,304
    float* htgt    = (float*)(ws + 5177408);      // 4,194,304
    float* ptab    = (float*)(ws + 9371712);      //   524,288
    float* V       = (float*)(ws + 9896000);      // 8,388,608
    float* c_wrb   = (float*)(ws + 18284608);     //     8,192
    float* c_av    = (float*)(ws + 18292800);     //       512
    float* c_Wo    = (float*)(ws + 18293312);     //     8,192
    float* c_Wg    = (float*)(ws + 18301504);     //     4,096
    float* c_W2    = (float*)(ws + 18305600);     //     4,096
    float* logitsw = (float*)(ws + 18309696);     // 7,864,320  (end ~26.2 MB)

    hipLaunchKernelGGL(knn_kernel, dim3(N_/4), dim3(256), 0, stream,
                       trans, x_mask, flag, srcArr);
    hipLaunchKernelGGL(prep_kernel, dim3(2048 + 512 + 8), dim3(256), 0, stream,
                       rots, node_emb, x_mask, noising_mask,
                       Wa, avec, Wv, Wo, Wg, W2, flag,
                       hsrc, htgt, ptab, V,
                       c_wrb, c_av, c_Wo, c_Wg, c_W2);
    hipLaunchKernelGGL(logits_kernel, dim3(E_/64), dim3(128), 0, stream,
                       trans, srcArr, hsrc, htgt, ptab, c_wrb, c_av, flag, logitsw);
    hipLaunchKernelGGL(agg_out_kernel, dim3(N_), dim3(256), 0, stream,
                       V, srcArr, logitsw, c_Wo, c_Wg, c_W2, flag, d_out);
}